// Round 1
// baseline (301.476 us; speedup 1.0000x reference)
//
#include <hip/hip_runtime.h>
#include <hip/hip_bf16.h>
#include <math.h>

#define N_NODES 10000
#define DIM 128
#define N_EDGES 640000
#define BN_EPS 1e-3f
#define TILE_R 16

__device__ __forceinline__ float gelu_exact(float x) {
  return 0.5f * x * (1.0f + erff(x * 0.70710678f));
}

// Fold BN (inference affine) into the following Dense:
// y = (x*s + t) @ W + bias  ==  x @ (diag(s)W) + (t@W + bias)
__global__ void fold_kernel(const float* __restrict__ g, const float* __restrict__ b,
                            const float* __restrict__ m, const float* __restrict__ v,
                            const float* __restrict__ W, const float* __restrict__ bias,
                            float* __restrict__ Wf, float* __restrict__ bf, int din) {
  __shared__ float s_sh[256];
  __shared__ float t_sh[256];
  int j = threadIdx.x;  // 0..127 (output col)
  for (int k = j; k < din; k += 128) {
    float s = g[k] / sqrtf(v[k] + BN_EPS);
    s_sh[k] = s;
    t_sh[k] = b[k] - m[k] * s;
  }
  __syncthreads();
  float acc = bias[j];
  for (int k = 0; k < din; ++k) {
    float wkj = W[k * 128 + j];
    Wf[k * 128 + j] = s_sh[k] * wkj;
    acc = fmaf(t_sh[k], wkj, acc);
  }
  bf[j] = acc;
}

// Per-node message: M[n] = gelu(gelu(x[n]@W1f+b1f)@W2f+b2f)
__global__ __launch_bounds__(128) void node_msg_kernel(
    const float* __restrict__ x,
    const float* __restrict__ W1, const float* __restrict__ b1,
    const float* __restrict__ W2, const float* __restrict__ b2,
    float* __restrict__ M, int n) {
  __shared__ float xs[TILE_R][128];
  __shared__ float h1[TILE_R][128];
  int j = threadIdx.x;
  int row0 = blockIdx.x * TILE_R;

  for (int r = 0; r < TILE_R; ++r) {
    int row = row0 + r;
    xs[r][j] = (row < n) ? x[(size_t)row * DIM + j] : 0.f;
  }
  __syncthreads();

  float acc[TILE_R];
  float bj = b1[j];
#pragma unroll
  for (int r = 0; r < TILE_R; ++r) acc[r] = bj;
  for (int k = 0; k < 128; k += 4) {
    float w0 = W1[(k + 0) * 128 + j];
    float w1 = W1[(k + 1) * 128 + j];
    float w2 = W1[(k + 2) * 128 + j];
    float w3 = W1[(k + 3) * 128 + j];
#pragma unroll
    for (int r = 0; r < TILE_R; ++r) {
      float4 xv = *reinterpret_cast<const float4*>(&xs[r][k]);
      acc[r] = fmaf(xv.x, w0, acc[r]);
      acc[r] = fmaf(xv.y, w1, acc[r]);
      acc[r] = fmaf(xv.z, w2, acc[r]);
      acc[r] = fmaf(xv.w, w3, acc[r]);
    }
  }
#pragma unroll
  for (int r = 0; r < TILE_R; ++r) h1[r][j] = gelu_exact(acc[r]);
  __syncthreads();

  float b2j = b2[j];
#pragma unroll
  for (int r = 0; r < TILE_R; ++r) acc[r] = b2j;
  for (int k = 0; k < 128; k += 4) {
    float w0 = W2[(k + 0) * 128 + j];
    float w1 = W2[(k + 1) * 128 + j];
    float w2 = W2[(k + 2) * 128 + j];
    float w3 = W2[(k + 3) * 128 + j];
#pragma unroll
    for (int r = 0; r < TILE_R; ++r) {
      float4 xv = *reinterpret_cast<const float4*>(&h1[r][k]);
      acc[r] = fmaf(xv.x, w0, acc[r]);
      acc[r] = fmaf(xv.y, w1, acc[r]);
      acc[r] = fmaf(xv.z, w2, acc[r]);
      acc[r] = fmaf(xv.w, w3, acc[r]);
    }
  }
#pragma unroll
  for (int r = 0; r < TILE_R; ++r) {
    int row = row0 + r;
    if (row < n) M[(size_t)row * DIM + j] = gelu_exact(acc[r]);
  }
}

__global__ void hist_kernel(const int* __restrict__ node_idx, int* __restrict__ hist, int e_count) {
  int e = blockIdx.x * blockDim.x + threadIdx.x;
  if (e < e_count) atomicAdd(&hist[node_idx[e]], 1);
}

// Single-block exclusive scan of hist[0..n) -> row_start[0..n], also copies to cursor.
__global__ void scan_kernel(const int* __restrict__ hist, int* __restrict__ row_start,
                            int* __restrict__ cursor, int n) {
  __shared__ int buf[1024];
  __shared__ int carry_s;
  int tid = threadIdx.x;
  if (tid == 0) carry_s = 0;
  __syncthreads();
  for (int base = 0; base < n; base += 1024) {
    int idx = base + tid;
    int vv = (idx < n) ? hist[idx] : 0;
    buf[tid] = vv;
    __syncthreads();
    for (int off = 1; off < 1024; off <<= 1) {
      int t = (tid >= off) ? buf[tid - off] : 0;
      __syncthreads();
      buf[tid] += t;
      __syncthreads();
    }
    int carry = carry_s;
    if (idx < n) {
      int excl = carry + buf[tid] - vv;
      row_start[idx] = excl;
      cursor[idx] = excl;
    }
    __syncthreads();
    if (tid == 1023) carry_s = carry + buf[1023];
    __syncthreads();
  }
  if (tid == 0) row_start[n] = carry_s;
}

__global__ void scatter_kernel(const int* __restrict__ node_idx, const int* __restrict__ nbr_idx,
                               const float* __restrict__ ew, int* __restrict__ cursor,
                               int* __restrict__ nbr_s, float* __restrict__ w_s, int e_count) {
  int e = blockIdx.x * blockDim.x + threadIdx.x;
  if (e < e_count) {
    int i = node_idx[e];
    int pos = atomicAdd(&cursor[i], 1);
    nbr_s[pos] = nbr_idx[e];
    w_s[pos] = ew[e];
  }
}

// agg[i] = (sum over CSR row i of w_e * M[nbr_e]) / max(cnt,1)
__global__ __launch_bounds__(128) void spmm_kernel(
    const int* __restrict__ row_start, const int* __restrict__ nbr_s,
    const float* __restrict__ w_s, const float* __restrict__ M,
    float* __restrict__ agg) {
  int i = blockIdx.x;
  int j = threadIdx.x;
  int s = row_start[i];
  int epos = row_start[i + 1];
  float acc = 0.f;
  for (int e = s; e < epos; ++e) {
    acc = fmaf(w_s[e], M[(size_t)nbr_s[e] * DIM + j], acc);
  }
  int cnt = epos - s;
  agg[(size_t)i * DIM + j] = acc / (float)(cnt > 0 ? cnt : 1);
}

// h = gelu(gelu([x,agg]@U1f+bu1)@U2f+bu2)
__global__ __launch_bounds__(128) void update_kernel(
    const float* __restrict__ x, const float* __restrict__ agg,
    const float* __restrict__ U1, const float* __restrict__ bu1,
    const float* __restrict__ U2, const float* __restrict__ bu2,
    float* __restrict__ out, int n) {
  __shared__ float xs[TILE_R][256];
  __shared__ float h1[TILE_R][128];
  int j = threadIdx.x;
  int row0 = blockIdx.x * TILE_R;

  for (int r = 0; r < TILE_R; ++r) {
    int row = row0 + r;
    if (row < n) {
      xs[r][j] = x[(size_t)row * DIM + j];
      xs[r][128 + j] = agg[(size_t)row * DIM + j];
    } else {
      xs[r][j] = 0.f;
      xs[r][128 + j] = 0.f;
    }
  }
  __syncthreads();

  float acc[TILE_R];
  float bj = bu1[j];
#pragma unroll
  for (int r = 0; r < TILE_R; ++r) acc[r] = bj;
  for (int k = 0; k < 256; k += 4) {
    float w0 = U1[(k + 0) * 128 + j];
    float w1 = U1[(k + 1) * 128 + j];
    float w2 = U1[(k + 2) * 128 + j];
    float w3 = U1[(k + 3) * 128 + j];
#pragma unroll
    for (int r = 0; r < TILE_R; ++r) {
      float4 xv = *reinterpret_cast<const float4*>(&xs[r][k]);
      acc[r] = fmaf(xv.x, w0, acc[r]);
      acc[r] = fmaf(xv.y, w1, acc[r]);
      acc[r] = fmaf(xv.z, w2, acc[r]);
      acc[r] = fmaf(xv.w, w3, acc[r]);
    }
  }
#pragma unroll
  for (int r = 0; r < TILE_R; ++r) h1[r][j] = gelu_exact(acc[r]);
  __syncthreads();

  float b2j = bu2[j];
#pragma unroll
  for (int r = 0; r < TILE_R; ++r) acc[r] = b2j;
  for (int k = 0; k < 128; k += 4) {
    float w0 = U2[(k + 0) * 128 + j];
    float w1 = U2[(k + 1) * 128 + j];
    float w2 = U2[(k + 2) * 128 + j];
    float w3 = U2[(k + 3) * 128 + j];
#pragma unroll
    for (int r = 0; r < TILE_R; ++r) {
      float4 xv = *reinterpret_cast<const float4*>(&h1[r][k]);
      acc[r] = fmaf(xv.x, w0, acc[r]);
      acc[r] = fmaf(xv.y, w1, acc[r]);
      acc[r] = fmaf(xv.z, w2, acc[r]);
      acc[r] = fmaf(xv.w, w3, acc[r]);
    }
  }
#pragma unroll
  for (int r = 0; r < TILE_R; ++r) {
    int row = row0 + r;
    if (row < n) out[(size_t)row * DIM + j] = gelu_exact(acc[r]);
  }
}

extern "C" void kernel_launch(void* const* d_in, const int* in_sizes, int n_in,
                              void* d_out, int out_size, void* d_ws, size_t ws_size,
                              hipStream_t stream) {
  const float* x = (const float*)d_in[0];
  const int* edges = (const int*)d_in[1];
  const float* ew = (const float*)d_in[2];
  const float* p1_g = (const float*)d_in[3];
  const float* p1_b = (const float*)d_in[4];
  const float* p1_m = (const float*)d_in[5];
  const float* p1_v = (const float*)d_in[6];
  const float* p1_W = (const float*)d_in[7];
  const float* p1_bias = (const float*)d_in[8];
  const float* p2_g = (const float*)d_in[9];
  const float* p2_b = (const float*)d_in[10];
  const float* p2_m = (const float*)d_in[11];
  const float* p2_v = (const float*)d_in[12];
  const float* p2_W = (const float*)d_in[13];
  const float* p2_bias = (const float*)d_in[14];
  const float* u1_g = (const float*)d_in[15];
  const float* u1_b = (const float*)d_in[16];
  const float* u1_m = (const float*)d_in[17];
  const float* u1_v = (const float*)d_in[18];
  const float* u1_W = (const float*)d_in[19];
  const float* u1_bias = (const float*)d_in[20];
  const float* u2_g = (const float*)d_in[21];
  const float* u2_b = (const float*)d_in[22];
  const float* u2_m = (const float*)d_in[23];
  const float* u2_v = (const float*)d_in[24];
  const float* u2_W = (const float*)d_in[25];
  const float* u2_bias = (const float*)d_in[26];

  const int* node_idx = edges;            // edges[0, :]
  const int* nbr_idx = edges + N_EDGES;   // edges[1, :]

  char* wsp = (char*)d_ws;
  auto alloc = [&](size_t bytes) {
    char* p = wsp;
    wsp += (bytes + 255) & ~(size_t)255;
    return p;
  };
  float* M = (float*)alloc((size_t)N_NODES * DIM * 4);
  float* agg = (float*)alloc((size_t)N_NODES * DIM * 4);
  float* W1f = (float*)alloc(128 * 128 * 4);
  float* b1f = (float*)alloc(128 * 4);
  float* W2f = (float*)alloc(128 * 128 * 4);
  float* b2f = (float*)alloc(128 * 4);
  float* U1f = (float*)alloc(256 * 128 * 4);
  float* bu1 = (float*)alloc(128 * 4);
  float* U2f = (float*)alloc(128 * 128 * 4);
  float* bu2 = (float*)alloc(128 * 4);
  int* hist = (int*)alloc(N_NODES * 4);
  int* cursor = (int*)alloc(N_NODES * 4);
  int* row_start = (int*)alloc((N_NODES + 1) * 4);
  int* nbr_s = (int*)alloc((size_t)N_EDGES * 4);
  float* w_s = (float*)alloc((size_t)N_EDGES * 4);

  hipMemsetAsync(hist, 0, N_NODES * 4, stream);

  fold_kernel<<<1, 128, 0, stream>>>(p1_g, p1_b, p1_m, p1_v, p1_W, p1_bias, W1f, b1f, 128);
  fold_kernel<<<1, 128, 0, stream>>>(p2_g, p2_b, p2_m, p2_v, p2_W, p2_bias, W2f, b2f, 128);
  fold_kernel<<<1, 128, 0, stream>>>(u1_g, u1_b, u1_m, u1_v, u1_W, u1_bias, U1f, bu1, 256);
  fold_kernel<<<1, 128, 0, stream>>>(u2_g, u2_b, u2_m, u2_v, u2_W, u2_bias, U2f, bu2, 128);

  int msg_blocks = (N_NODES + TILE_R - 1) / TILE_R;
  node_msg_kernel<<<msg_blocks, 128, 0, stream>>>(x, W1f, b1f, W2f, b2f, M, N_NODES);

  int eb = (N_EDGES + 255) / 256;
  hist_kernel<<<eb, 256, 0, stream>>>(node_idx, hist, N_EDGES);
  scan_kernel<<<1, 1024, 0, stream>>>(hist, row_start, cursor, N_NODES);
  scatter_kernel<<<eb, 256, 0, stream>>>(node_idx, nbr_idx, ew, cursor, nbr_s, w_s, N_EDGES);
  spmm_kernel<<<N_NODES, 128, 0, stream>>>(row_start, nbr_s, w_s, M, agg);

  update_kernel<<<msg_blocks, 128, 0, stream>>>(x, agg, U1f, bu1, U2f, bu2, (float*)d_out, N_NODES);
}

// Round 2
// 272.160 us; speedup vs baseline: 1.1077x; 1.1077x over previous
//
#include <hip/hip_runtime.h>
#include <hip/hip_bf16.h>
#include <hip/hip_fp16.h>
#include <math.h>

#define N_NODES 10000
#define DIM 128
#define N_EDGES 640000
#define BN_EPS 1e-3f
#define TILE_R 16

__device__ __forceinline__ float gelu_exact(float x) {
  return 0.5f * x * (1.0f + erff(x * 0.70710678f));
}

struct FoldParams {
  const float *g, *b, *m, *v, *W, *bias;
  float *Wf, *bf;
  int din;
};

// Fused BN-fold: y = (x*s + t) @ W + bias == x @ (diag(s)W) + (t@W + bias)
// grid = (1 + 9, 4): x==0 computes folded bias; x>=1 scales 32 rows of W each.
__global__ __launch_bounds__(256) void fold_fused_kernel(FoldParams p0, FoldParams p1,
                                                         FoldParams p2, FoldParams p3) {
  FoldParams ps[4] = {p0, p1, p2, p3};
  FoldParams p = ps[blockIdx.y];
  int t = threadIdx.x;
  if (blockIdx.x == 0) {
    __shared__ float t_sh[256];
    for (int k = t; k < p.din; k += 256) {
      float s = p.g[k] * rsqrtf(p.v[k] + BN_EPS);
      t_sh[k] = p.b[k] - p.m[k] * s;
    }
    __syncthreads();
    if (t < 128) {
      float acc = p.bias[t];
      for (int k = 0; k < p.din; ++k) acc = fmaf(t_sh[k], p.W[k * 128 + t], acc);
      p.bf[t] = acc;
    }
  } else {
    int base = (blockIdx.x - 1) * 32;  // first row this block scales
    if (base >= p.din) return;
#pragma unroll
    for (int it = 0; it < 16; ++it) {
      int off = it * 256 + t;
      int k = base + (off >> 7);
      int j = off & 127;
      if (k < p.din) {
        float s = p.g[k] * rsqrtf(p.v[k] + BN_EPS);
        p.Wf[k * 128 + j] = s * p.W[k * 128 + j];
      }
    }
  }
}

// Per-node message: M[n] = fp16( gelu(gelu(x[n]@W1f+b1f)@W2f+b2f) )
__global__ __launch_bounds__(128) void node_msg_kernel(
    const float* __restrict__ x,
    const float* __restrict__ W1, const float* __restrict__ b1,
    const float* __restrict__ W2, const float* __restrict__ b2,
    __half* __restrict__ M, int n) {
  __shared__ float xs[TILE_R][128];
  __shared__ float h1[TILE_R][128];
  int j = threadIdx.x;
  int row0 = blockIdx.x * TILE_R;

  for (int r = 0; r < TILE_R; ++r) {
    int row = row0 + r;
    xs[r][j] = (row < n) ? x[(size_t)row * DIM + j] : 0.f;
  }
  __syncthreads();

  float acc[TILE_R];
  float bj = b1[j];
#pragma unroll
  for (int r = 0; r < TILE_R; ++r) acc[r] = bj;
  for (int k = 0; k < 128; k += 4) {
    float w0 = W1[(k + 0) * 128 + j];
    float w1 = W1[(k + 1) * 128 + j];
    float w2 = W1[(k + 2) * 128 + j];
    float w3 = W1[(k + 3) * 128 + j];
#pragma unroll
    for (int r = 0; r < TILE_R; ++r) {
      float4 xv = *reinterpret_cast<const float4*>(&xs[r][k]);
      acc[r] = fmaf(xv.x, w0, acc[r]);
      acc[r] = fmaf(xv.y, w1, acc[r]);
      acc[r] = fmaf(xv.z, w2, acc[r]);
      acc[r] = fmaf(xv.w, w3, acc[r]);
    }
  }
#pragma unroll
  for (int r = 0; r < TILE_R; ++r) h1[r][j] = gelu_exact(acc[r]);
  __syncthreads();

  float b2j = b2[j];
#pragma unroll
  for (int r = 0; r < TILE_R; ++r) acc[r] = b2j;
  for (int k = 0; k < 128; k += 4) {
    float w0 = W2[(k + 0) * 128 + j];
    float w1 = W2[(k + 1) * 128 + j];
    float w2 = W2[(k + 2) * 128 + j];
    float w3 = W2[(k + 3) * 128 + j];
#pragma unroll
    for (int r = 0; r < TILE_R; ++r) {
      float4 xv = *reinterpret_cast<const float4*>(&h1[r][k]);
      acc[r] = fmaf(xv.x, w0, acc[r]);
      acc[r] = fmaf(xv.y, w1, acc[r]);
      acc[r] = fmaf(xv.z, w2, acc[r]);
      acc[r] = fmaf(xv.w, w3, acc[r]);
    }
  }
#pragma unroll
  for (int r = 0; r < TILE_R; ++r) {
    int row = row0 + r;
    if (row < n) M[(size_t)row * DIM + j] = __float2half(gelu_exact(acc[r]));
  }
}

__global__ void hist_kernel(const int* __restrict__ node_idx, int* __restrict__ hist, int e_count) {
  int e = blockIdx.x * blockDim.x + threadIdx.x;
  if (e < e_count) atomicAdd(&hist[node_idx[e]], 1);
}

// One block, 256 threads, each owns 40 contiguous elements.
__global__ __launch_bounds__(256) void scan_kernel(const int* __restrict__ hist,
                                                   int* __restrict__ row_start,
                                                   int* __restrict__ cursor, int n) {
  const int PER = 40;
  __shared__ int sums[256];
  int t = threadIdx.x;
  int i0 = t * PER;
  int total = 0;
  for (int i = 0; i < PER; ++i) {
    int idx = i0 + i;
    total += (idx < n) ? hist[idx] : 0;
  }
  sums[t] = total;
  __syncthreads();
  // Hillis-Steele inclusive scan over 256 partials
  for (int off = 1; off < 256; off <<= 1) {
    int v = (t >= off) ? sums[t - off] : 0;
    __syncthreads();
    sums[t] += v;
    __syncthreads();
  }
  int running = sums[t] - total;  // exclusive prefix for this thread's chunk
  for (int i = 0; i < PER; ++i) {
    int idx = i0 + i;
    if (idx < n) {
      row_start[idx] = running;
      cursor[idx] = running;
      running += hist[idx];
    }
  }
  if (t == 255) row_start[n] = sums[255];
}

// Pack (nbr, weight) into uint2 per edge, CSR-ordered.
__global__ void scatter_kernel(const int* __restrict__ node_idx, const int* __restrict__ nbr_idx,
                               const float* __restrict__ ew, int* __restrict__ cursor,
                               uint2* __restrict__ edge_s, int e_count) {
  int e = blockIdx.x * blockDim.x + threadIdx.x;
  if (e < e_count) {
    int i = node_idx[e];
    int pos = atomicAdd(&cursor[i], 1);
    uint2 pk;
    pk.x = (unsigned)nbr_idx[e];
    pk.y = __float_as_uint(ew[e]);
    edge_s[pos] = pk;
  }
}

// agg[i] = (sum over CSR row i of w_e * M[nbr_e]) / max(cnt,1)
// 256 threads: 8 edge-slices x 32 col-groups (float4 of halves each).
__global__ __launch_bounds__(256) void spmm_kernel(
    const int* __restrict__ row_start, const uint2* __restrict__ edge_s,
    const __half* __restrict__ M, float* __restrict__ agg) {
  __shared__ float4 red4[8][32];
  int i = blockIdx.x;
  int t = threadIdx.x;
  int cg = t & 31;      // column group: columns 4*cg .. 4*cg+3
  int slice = t >> 5;   // edge slice 0..7
  int s = row_start[i];
  int e_end = row_start[i + 1];

  float a0 = 0.f, a1 = 0.f, a2 = 0.f, a3 = 0.f;
  int e = s + slice;
  if (e < e_end) {
    uint2 pk = edge_s[e];
    for (; e < e_end; e += 8) {
      int en = e + 8;
      uint2 nxt = (en < e_end) ? edge_s[en] : pk;
      unsigned nbr = pk.x;
      float w = __uint_as_float(pk.y);
      uint2 raw = *reinterpret_cast<const uint2*>(M + (size_t)nbr * DIM + cg * 4);
      __half2 h01 = *reinterpret_cast<__half2*>(&raw.x);
      __half2 h23 = *reinterpret_cast<__half2*>(&raw.y);
      float2 f01 = __half22float2(h01);
      float2 f23 = __half22float2(h23);
      a0 = fmaf(w, f01.x, a0);
      a1 = fmaf(w, f01.y, a1);
      a2 = fmaf(w, f23.x, a2);
      a3 = fmaf(w, f23.y, a3);
      pk = nxt;
    }
  }
  red4[slice][cg] = make_float4(a0, a1, a2, a3);
  __syncthreads();

  if (t < 128) {
    const float* redf = (const float*)red4;
    float acc = 0.f;
#pragma unroll
    for (int sl = 0; sl < 8; ++sl) acc += redf[sl * 128 + t];
    int cnt = e_end - s;
    agg[(size_t)i * DIM + t] = acc / (float)(cnt > 0 ? cnt : 1);
  }
}

// h = gelu(gelu([x,agg]@U1f+bu1)@U2f+bu2)
__global__ __launch_bounds__(128) void update_kernel(
    const float* __restrict__ x, const float* __restrict__ agg,
    const float* __restrict__ U1, const float* __restrict__ bu1,
    const float* __restrict__ U2, const float* __restrict__ bu2,
    float* __restrict__ out, int n) {
  __shared__ float xs[TILE_R][256];
  __shared__ float h1[TILE_R][128];
  int j = threadIdx.x;
  int row0 = blockIdx.x * TILE_R;

  for (int r = 0; r < TILE_R; ++r) {
    int row = row0 + r;
    if (row < n) {
      xs[r][j] = x[(size_t)row * DIM + j];
      xs[r][128 + j] = agg[(size_t)row * DIM + j];
    } else {
      xs[r][j] = 0.f;
      xs[r][128 + j] = 0.f;
    }
  }
  __syncthreads();

  float acc[TILE_R];
  float bj = bu1[j];
#pragma unroll
  for (int r = 0; r < TILE_R; ++r) acc[r] = bj;
  for (int k = 0; k < 256; k += 4) {
    float w0 = U1[(k + 0) * 128 + j];
    float w1 = U1[(k + 1) * 128 + j];
    float w2 = U1[(k + 2) * 128 + j];
    float w3 = U1[(k + 3) * 128 + j];
#pragma unroll
    for (int r = 0; r < TILE_R; ++r) {
      float4 xv = *reinterpret_cast<const float4*>(&xs[r][k]);
      acc[r] = fmaf(xv.x, w0, acc[r]);
      acc[r] = fmaf(xv.y, w1, acc[r]);
      acc[r] = fmaf(xv.z, w2, acc[r]);
      acc[r] = fmaf(xv.w, w3, acc[r]);
    }
  }
#pragma unroll
  for (int r = 0; r < TILE_R; ++r) h1[r][j] = gelu_exact(acc[r]);
  __syncthreads();

  float b2j = bu2[j];
#pragma unroll
  for (int r = 0; r < TILE_R; ++r) acc[r] = b2j;
  for (int k = 0; k < 128; k += 4) {
    float w0 = U2[(k + 0) * 128 + j];
    float w1 = U2[(k + 1) * 128 + j];
    float w2 = U2[(k + 2) * 128 + j];
    float w3 = U2[(k + 3) * 128 + j];
#pragma unroll
    for (int r = 0; r < TILE_R; ++r) {
      float4 xv = *reinterpret_cast<const float4*>(&h1[r][k]);
      acc[r] = fmaf(xv.x, w0, acc[r]);
      acc[r] = fmaf(xv.y, w1, acc[r]);
      acc[r] = fmaf(xv.z, w2, acc[r]);
      acc[r] = fmaf(xv.w, w3, acc[r]);
    }
  }
#pragma unroll
  for (int r = 0; r < TILE_R; ++r) {
    int row = row0 + r;
    if (row < n) out[(size_t)row * DIM + j] = gelu_exact(acc[r]);
  }
}

extern "C" void kernel_launch(void* const* d_in, const int* in_sizes, int n_in,
                              void* d_out, int out_size, void* d_ws, size_t ws_size,
                              hipStream_t stream) {
  const float* x = (const float*)d_in[0];
  const int* edges = (const int*)d_in[1];
  const float* ew = (const float*)d_in[2];
  const float* p1_g = (const float*)d_in[3];
  const float* p1_b = (const float*)d_in[4];
  const float* p1_m = (const float*)d_in[5];
  const float* p1_v = (const float*)d_in[6];
  const float* p1_W = (const float*)d_in[7];
  const float* p1_bias = (const float*)d_in[8];
  const float* p2_g = (const float*)d_in[9];
  const float* p2_b = (const float*)d_in[10];
  const float* p2_m = (const float*)d_in[11];
  const float* p2_v = (const float*)d_in[12];
  const float* p2_W = (const float*)d_in[13];
  const float* p2_bias = (const float*)d_in[14];
  const float* u1_g = (const float*)d_in[15];
  const float* u1_b = (const float*)d_in[16];
  const float* u1_m = (const float*)d_in[17];
  const float* u1_v = (const float*)d_in[18];
  const float* u1_W = (const float*)d_in[19];
  const float* u1_bias = (const float*)d_in[20];
  const float* u2_g = (const float*)d_in[21];
  const float* u2_b = (const float*)d_in[22];
  const float* u2_m = (const float*)d_in[23];
  const float* u2_v = (const float*)d_in[24];
  const float* u2_W = (const float*)d_in[25];
  const float* u2_bias = (const float*)d_in[26];

  const int* node_idx = edges;            // edges[0, :]
  const int* nbr_idx = edges + N_EDGES;   // edges[1, :]

  char* wsp = (char*)d_ws;
  auto alloc = [&](size_t bytes) {
    char* p = wsp;
    wsp += (bytes + 255) & ~(size_t)255;
    return p;
  };
  __half* M = (__half*)alloc((size_t)N_NODES * DIM * 2);
  float* agg = (float*)alloc((size_t)N_NODES * DIM * 4);
  float* W1f = (float*)alloc(128 * 128 * 4);
  float* b1f = (float*)alloc(128 * 4);
  float* W2f = (float*)alloc(128 * 128 * 4);
  float* b2f = (float*)alloc(128 * 4);
  float* U1f = (float*)alloc(256 * 128 * 4);
  float* bu1 = (float*)alloc(128 * 4);
  float* U2f = (float*)alloc(128 * 128 * 4);
  float* bu2 = (float*)alloc(128 * 4);
  int* hist = (int*)alloc(N_NODES * 4);
  int* cursor = (int*)alloc(N_NODES * 4);
  int* row_start = (int*)alloc((N_NODES + 1) * 4);
  uint2* edge_s = (uint2*)alloc((size_t)N_EDGES * 8);

  hipMemsetAsync(hist, 0, N_NODES * 4, stream);

  FoldParams fp1 = {p1_g, p1_b, p1_m, p1_v, p1_W, p1_bias, W1f, b1f, 128};
  FoldParams fp2 = {p2_g, p2_b, p2_m, p2_v, p2_W, p2_bias, W2f, b2f, 128};
  FoldParams fu1 = {u1_g, u1_b, u1_m, u1_v, u1_W, u1_bias, U1f, bu1, 256};
  FoldParams fu2 = {u2_g, u2_b, u2_m, u2_v, u2_W, u2_bias, U2f, bu2, 128};
  fold_fused_kernel<<<dim3(10, 4), 256, 0, stream>>>(fp1, fp2, fu1, fu2);

  int eb = (N_EDGES + 255) / 256;
  hist_kernel<<<eb, 256, 0, stream>>>(node_idx, hist, N_EDGES);
  scan_kernel<<<1, 256, 0, stream>>>(hist, row_start, cursor, N_NODES);

  int msg_blocks = (N_NODES + TILE_R - 1) / TILE_R;
  node_msg_kernel<<<msg_blocks, 128, 0, stream>>>(x, W1f, b1f, W2f, b2f, M, N_NODES);

  scatter_kernel<<<eb, 256, 0, stream>>>(node_idx, nbr_idx, ew, cursor, edge_s, N_EDGES);
  spmm_kernel<<<N_NODES, 256, 0, stream>>>(row_start, edge_s, M, agg);

  update_kernel<<<msg_blocks, 128, 0, stream>>>(x, agg, U1f, bu1, U2f, bu2, (float*)d_out, N_NODES);
}

// Round 3
// 237.486 us; speedup vs baseline: 1.2695x; 1.1460x over previous
//
#include <hip/hip_runtime.h>
#include <hip/hip_bf16.h>
#include <hip/hip_fp16.h>
#include <math.h>

#define N_NODES 10000
#define DIM 128
#define N_EDGES 640000
#define BN_EPS 1e-3f
#define TR 8
#define MSG_BLOCKS 1250   // 10000 / TR
#define HIST_BLOCKS 625   // 640000 / (256*4)

__device__ __forceinline__ float gelu_exact(float x) {
  return 0.5f * x * (1.0f + erff(x * 0.70710678f));
}

struct FoldParams {
  const float *g, *b, *m, *v, *W, *bias;
  float *Wf, *bf;
  int din;
};

// Fused BN-fold: y = (x*s + t) @ W + bias == x @ (diag(s)W) + (t@W + bias)
// grid = (20, 4). x==0: folded bias (k-split GEMV). x in [1,9]: scale 32 W-rows
// each. x in [10,19]: zero hist (each (x,y) block zeros 256 entries).
__global__ __launch_bounds__(256) void fold_fused_kernel(FoldParams p0, FoldParams p1,
                                                         FoldParams p2, FoldParams p3,
                                                         int* __restrict__ hist) {
  int t = threadIdx.x;
  if (blockIdx.x >= 10) {
    int lin = (blockIdx.x - 10) * 4 + blockIdx.y;
    int idx = lin * 256 + t;
    if (idx < N_NODES) hist[idx] = 0;
    return;
  }
  FoldParams p = (blockIdx.y == 0) ? p0 : (blockIdx.y == 1) ? p1 : (blockIdx.y == 2) ? p2 : p3;
  if (blockIdx.x == 0) {
    __shared__ float t_sh[256];
    __shared__ float bpart[128];
    for (int k = t; k < p.din; k += 256) {
      float s = p.g[k] * rsqrtf(p.v[k] + BN_EPS);
      t_sh[k] = p.b[k] - p.m[k] * s;
    }
    __syncthreads();
    int j = t & 127, kh = t >> 7;
    int half = p.din >> 1;
    float acc = 0.f;
    for (int k = kh * half; k < (kh + 1) * half; ++k)
      acc = fmaf(t_sh[k], p.W[k * 128 + j], acc);
    if (kh == 1) bpart[j] = acc;
    __syncthreads();
    if (kh == 0) p.bf[j] = acc + bpart[j] + p.bias[j];
  } else {
    int base = (blockIdx.x - 1) * 32;  // first row this block scales
    if (base >= p.din) return;
#pragma unroll
    for (int it = 0; it < 16; ++it) {
      int off = it * 256 + t;
      int k = base + (off >> 7);
      int j = off & 127;
      if (k < p.din) {
        float s = p.g[k] * rsqrtf(p.v[k] + BN_EPS);
        p.Wf[k * 128 + j] = s * p.W[k * 128 + j];
      }
    }
  }
}

// Merged: blocks [0, MSG_BLOCKS) compute per-node message M (fp16);
// blocks [MSG_BLOCKS, MSG_BLOCKS+HIST_BLOCKS) histogram dst-degrees.
__global__ __launch_bounds__(256) void msg_hist_kernel(
    const float* __restrict__ x,
    const float* __restrict__ W1, const float* __restrict__ b1,
    const float* __restrict__ W2, const float* __restrict__ b2,
    __half* __restrict__ M,
    const int* __restrict__ node_idx, int* __restrict__ hist) {
  int bx = blockIdx.x;
  int t = threadIdx.x;
  if (bx >= MSG_BLOCKS) {
    int base = ((bx - MSG_BLOCKS) * 256 + t) * 4;
    if (base < N_EDGES) {
      int4 v = *reinterpret_cast<const int4*>(&node_idx[base]);
      atomicAdd(&hist[v.x], 1);
      atomicAdd(&hist[v.y], 1);
      atomicAdd(&hist[v.z], 1);
      atomicAdd(&hist[v.w], 1);
    }
    return;
  }
  __shared__ float xs[TR][128];   // inputs, then reused as h1
  __shared__ float red[TR][128];  // k-half partial reduce
  int j = t & 127, kh = t >> 7;
  int row0 = bx * TR;

  for (int idx = t; idx < TR * 128; idx += 256) {
    int r = idx >> 7, c = idx & 127;
    int row = row0 + r;
    xs[r][c] = (row < N_NODES) ? x[(size_t)row * DIM + c] : 0.f;
  }
  __syncthreads();

  float acc[TR];
#pragma unroll
  for (int r = 0; r < TR; ++r) acc[r] = 0.f;
  {
    int k0 = kh * 64;
    for (int k = k0; k < k0 + 64; k += 4) {
      float w0 = W1[(k + 0) * 128 + j];
      float w1 = W1[(k + 1) * 128 + j];
      float w2 = W1[(k + 2) * 128 + j];
      float w3 = W1[(k + 3) * 128 + j];
#pragma unroll
      for (int r = 0; r < TR; ++r) {
        float4 xv = *reinterpret_cast<const float4*>(&xs[r][k]);
        acc[r] = fmaf(xv.x, w0, acc[r]);
        acc[r] = fmaf(xv.y, w1, acc[r]);
        acc[r] = fmaf(xv.z, w2, acc[r]);
        acc[r] = fmaf(xv.w, w3, acc[r]);
      }
    }
  }
  if (kh == 1) {
#pragma unroll
    for (int r = 0; r < TR; ++r) red[r][j] = acc[r];
  }
  __syncthreads();
  if (kh == 0) {
    float bj = b1[j];
#pragma unroll
    for (int r = 0; r < TR; ++r) xs[r][j] = gelu_exact(acc[r] + red[r][j] + bj);
  }
  __syncthreads();

#pragma unroll
  for (int r = 0; r < TR; ++r) acc[r] = 0.f;
  {
    int k0 = kh * 64;
    for (int k = k0; k < k0 + 64; k += 4) {
      float w0 = W2[(k + 0) * 128 + j];
      float w1 = W2[(k + 1) * 128 + j];
      float w2 = W2[(k + 2) * 128 + j];
      float w3 = W2[(k + 3) * 128 + j];
#pragma unroll
      for (int r = 0; r < TR; ++r) {
        float4 xv = *reinterpret_cast<const float4*>(&xs[r][k]);
        acc[r] = fmaf(xv.x, w0, acc[r]);
        acc[r] = fmaf(xv.y, w1, acc[r]);
        acc[r] = fmaf(xv.z, w2, acc[r]);
        acc[r] = fmaf(xv.w, w3, acc[r]);
      }
    }
  }
  if (kh == 1) {
#pragma unroll
    for (int r = 0; r < TR; ++r) red[r][j] = acc[r];
  }
  __syncthreads();
  if (kh == 0) {
    float bj = b2[j];
#pragma unroll
    for (int r = 0; r < TR; ++r) {
      int row = row0 + r;
      if (row < N_NODES)
        M[(size_t)row * DIM + j] = __float2half(gelu_exact(acc[r] + red[r][j] + bj));
    }
  }
}

// One block, 256 threads, each owns 40 contiguous elements.
__global__ __launch_bounds__(256) void scan_kernel(const int* __restrict__ hist,
                                                   int* __restrict__ row_start,
                                                   int* __restrict__ cursor, int n) {
  const int PER = 40;
  __shared__ int sums[256];
  int t = threadIdx.x;
  int i0 = t * PER;
  int total = 0;
  for (int i = 0; i < PER; ++i) {
    int idx = i0 + i;
    total += (idx < n) ? hist[idx] : 0;
  }
  sums[t] = total;
  __syncthreads();
  for (int off = 1; off < 256; off <<= 1) {
    int v = (t >= off) ? sums[t - off] : 0;
    __syncthreads();
    sums[t] += v;
    __syncthreads();
  }
  int running = sums[t] - total;
  for (int i = 0; i < PER; ++i) {
    int idx = i0 + i;
    if (idx < n) {
      row_start[idx] = running;
      cursor[idx] = running;
      running += hist[idx];
    }
  }
  if (t == 255) row_start[n] = sums[255];
}

// Pack (nbr, weight) into uint2 per edge, CSR-ordered. 4 edges/thread.
__global__ __launch_bounds__(256) void scatter_kernel(
    const int* __restrict__ node_idx, const int* __restrict__ nbr_idx,
    const float* __restrict__ ew, int* __restrict__ cursor,
    uint2* __restrict__ edge_s) {
  int base = (blockIdx.x * 256 + threadIdx.x) * 4;
  if (base >= N_EDGES) return;
  int4 ni = *reinterpret_cast<const int4*>(&node_idx[base]);
  int4 nb = *reinterpret_cast<const int4*>(&nbr_idx[base]);
  float4 wv = *reinterpret_cast<const float4*>(&ew[base]);
  int p0 = atomicAdd(&cursor[ni.x], 1);
  edge_s[p0] = make_uint2((unsigned)nb.x, __float_as_uint(wv.x));
  int p1 = atomicAdd(&cursor[ni.y], 1);
  edge_s[p1] = make_uint2((unsigned)nb.y, __float_as_uint(wv.y));
  int p2 = atomicAdd(&cursor[ni.z], 1);
  edge_s[p2] = make_uint2((unsigned)nb.z, __float_as_uint(wv.z));
  int p3 = atomicAdd(&cursor[ni.w], 1);
  edge_s[p3] = make_uint2((unsigned)nb.w, __float_as_uint(wv.w));
}

// agg[i] = (sum over CSR row i of w_e * M[nbr_e]) / max(cnt,1)
// 256 threads: 8 edge-slices x 32 col-groups (4 halves each).
__global__ __launch_bounds__(256) void spmm_kernel(
    const int* __restrict__ row_start, const uint2* __restrict__ edge_s,
    const __half* __restrict__ M, float* __restrict__ agg) {
  __shared__ float4 red4[8][32];
  int i = blockIdx.x;
  int t = threadIdx.x;
  int cg = t & 31;
  int slice = t >> 5;
  int s = row_start[i];
  int e_end = row_start[i + 1];

  float a0 = 0.f, a1 = 0.f, a2 = 0.f, a3 = 0.f;
  int e = s + slice;
  if (e < e_end) {
    uint2 pk = edge_s[e];
    for (; e < e_end; e += 8) {
      int en = e + 8;
      uint2 nxt = (en < e_end) ? edge_s[en] : pk;
      unsigned nbr = pk.x;
      float w = __uint_as_float(pk.y);
      uint2 raw = *reinterpret_cast<const uint2*>(M + (size_t)nbr * DIM + cg * 4);
      __half2 h01 = *reinterpret_cast<__half2*>(&raw.x);
      __half2 h23 = *reinterpret_cast<__half2*>(&raw.y);
      float2 f01 = __half22float2(h01);
      float2 f23 = __half22float2(h23);
      a0 = fmaf(w, f01.x, a0);
      a1 = fmaf(w, f01.y, a1);
      a2 = fmaf(w, f23.x, a2);
      a3 = fmaf(w, f23.y, a3);
      pk = nxt;
    }
  }
  red4[slice][cg] = make_float4(a0, a1, a2, a3);
  __syncthreads();

  if (t < 128) {
    const float* redf = (const float*)red4;
    float acc = 0.f;
#pragma unroll
    for (int sl = 0; sl < 8; ++sl) acc += redf[sl * 128 + t];
    int cnt = e_end - s;
    agg[(size_t)i * DIM + t] = acc / (float)(cnt > 0 ? cnt : 1);
  }
}

// h = gelu(gelu([x,agg]@U1f+bu1)@U2f+bu2), k-split across thread halves.
__global__ __launch_bounds__(256) void update_kernel(
    const float* __restrict__ x, const float* __restrict__ agg,
    const float* __restrict__ U1, const float* __restrict__ bu1,
    const float* __restrict__ U2, const float* __restrict__ bu2,
    float* __restrict__ out) {
  __shared__ float xs[TR][256];   // concat input; cols 0..127 reused as h1
  __shared__ float red[TR][128];
  int t = threadIdx.x;
  int j = t & 127, kh = t >> 7;
  int row0 = blockIdx.x * TR;

  for (int idx = t; idx < TR * 256; idx += 256) {
    int r = idx >> 8, c = idx & 255;
    int row = row0 + r;
    float v = 0.f;
    if (row < N_NODES)
      v = (c < 128) ? x[(size_t)row * DIM + c] : agg[(size_t)row * DIM + (c - 128)];
    xs[r][c] = v;
  }
  __syncthreads();

  float acc[TR];
#pragma unroll
  for (int r = 0; r < TR; ++r) acc[r] = 0.f;
  {
    int k0 = kh * 128;
    for (int k = k0; k < k0 + 128; k += 4) {
      float w0 = U1[(k + 0) * 128 + j];
      float w1 = U1[(k + 1) * 128 + j];
      float w2 = U1[(k + 2) * 128 + j];
      float w3 = U1[(k + 3) * 128 + j];
#pragma unroll
      for (int r = 0; r < TR; ++r) {
        float4 xv = *reinterpret_cast<const float4*>(&xs[r][k]);
        acc[r] = fmaf(xv.x, w0, acc[r]);
        acc[r] = fmaf(xv.y, w1, acc[r]);
        acc[r] = fmaf(xv.z, w2, acc[r]);
        acc[r] = fmaf(xv.w, w3, acc[r]);
      }
    }
  }
  if (kh == 1) {
#pragma unroll
    for (int r = 0; r < TR; ++r) red[r][j] = acc[r];
  }
  __syncthreads();
  if (kh == 0) {
    float bj = bu1[j];
#pragma unroll
    for (int r = 0; r < TR; ++r) xs[r][j] = gelu_exact(acc[r] + red[r][j] + bj);
  }
  __syncthreads();

#pragma unroll
  for (int r = 0; r < TR; ++r) acc[r] = 0.f;
  {
    int k0 = kh * 64;
    for (int k = k0; k < k0 + 64; k += 4) {
      float w0 = U2[(k + 0) * 128 + j];
      float w1 = U2[(k + 1) * 128 + j];
      float w2 = U2[(k + 2) * 128 + j];
      float w3 = U2[(k + 3) * 128 + j];
#pragma unroll
      for (int r = 0; r < TR; ++r) {
        float4 xv = *reinterpret_cast<const float4*>(&xs[r][k]);
        acc[r] = fmaf(xv.x, w0, acc[r]);
        acc[r] = fmaf(xv.y, w1, acc[r]);
        acc[r] = fmaf(xv.z, w2, acc[r]);
        acc[r] = fmaf(xv.w, w3, acc[r]);
      }
    }
  }
  if (kh == 1) {
#pragma unroll
    for (int r = 0; r < TR; ++r) red[r][j] = acc[r];
  }
  __syncthreads();
  if (kh == 0) {
    float bj = bu2[j];
#pragma unroll
    for (int r = 0; r < TR; ++r) {
      int row = row0 + r;
      if (row < N_NODES)
        out[(size_t)row * DIM + j] = gelu_exact(acc[r] + red[r][j] + bj);
    }
  }
}

extern "C" void kernel_launch(void* const* d_in, const int* in_sizes, int n_in,
                              void* d_out, int out_size, void* d_ws, size_t ws_size,
                              hipStream_t stream) {
  const float* x = (const float*)d_in[0];
  const int* edges = (const int*)d_in[1];
  const float* ew = (const float*)d_in[2];
  const float* p1_g = (const float*)d_in[3];
  const float* p1_b = (const float*)d_in[4];
  const float* p1_m = (const float*)d_in[5];
  const float* p1_v = (const float*)d_in[6];
  const float* p1_W = (const float*)d_in[7];
  const float* p1_bias = (const float*)d_in[8];
  const float* p2_g = (const float*)d_in[9];
  const float* p2_b = (const float*)d_in[10];
  const float* p2_m = (const float*)d_in[11];
  const float* p2_v = (const float*)d_in[12];
  const float* p2_W = (const float*)d_in[13];
  const float* p2_bias = (const float*)d_in[14];
  const float* u1_g = (const float*)d_in[15];
  const float* u1_b = (const float*)d_in[16];
  const float* u1_m = (const float*)d_in[17];
  const float* u1_v = (const float*)d_in[18];
  const float* u1_W = (const float*)d_in[19];
  const float* u1_bias = (const float*)d_in[20];
  const float* u2_g = (const float*)d_in[21];
  const float* u2_b = (const float*)d_in[22];
  const float* u2_m = (const float*)d_in[23];
  const float* u2_v = (const float*)d_in[24];
  const float* u2_W = (const float*)d_in[25];
  const float* u2_bias = (const float*)d_in[26];

  const int* node_idx = edges;            // edges[0, :]
  const int* nbr_idx = edges + N_EDGES;   // edges[1, :]

  char* wsp = (char*)d_ws;
  auto alloc = [&](size_t bytes) {
    char* p = wsp;
    wsp += (bytes + 255) & ~(size_t)255;
    return p;
  };
  __half* M = (__half*)alloc((size_t)N_NODES * DIM * 2);
  float* agg = (float*)alloc((size_t)N_NODES * DIM * 4);
  float* W1f = (float*)alloc(128 * 128 * 4);
  float* b1f = (float*)alloc(128 * 4);
  float* W2f = (float*)alloc(128 * 128 * 4);
  float* b2f = (float*)alloc(128 * 4);
  float* U1f = (float*)alloc(256 * 128 * 4);
  float* bu1 = (float*)alloc(128 * 4);
  float* U2f = (float*)alloc(128 * 128 * 4);
  float* bu2 = (float*)alloc(128 * 4);
  int* hist = (int*)alloc(N_NODES * 4);
  int* cursor = (int*)alloc(N_NODES * 4);
  int* row_start = (int*)alloc((N_NODES + 1) * 4);
  uint2* edge_s = (uint2*)alloc((size_t)N_EDGES * 8);

  FoldParams fp1 = {p1_g, p1_b, p1_m, p1_v, p1_W, p1_bias, W1f, b1f, 128};
  FoldParams fp2 = {p2_g, p2_b, p2_m, p2_v, p2_W, p2_bias, W2f, b2f, 128};
  FoldParams fu1 = {u1_g, u1_b, u1_m, u1_v, u1_W, u1_bias, U1f, bu1, 256};
  FoldParams fu2 = {u2_g, u2_b, u2_m, u2_v, u2_W, u2_bias, U2f, bu2, 128};
  fold_fused_kernel<<<dim3(20, 4), 256, 0, stream>>>(fp1, fp2, fu1, fu2, hist);

  msg_hist_kernel<<<MSG_BLOCKS + HIST_BLOCKS, 256, 0, stream>>>(
      x, W1f, b1f, W2f, b2f, M, node_idx, hist);

  scan_kernel<<<1, 256, 0, stream>>>(hist, row_start, cursor, N_NODES);
  scatter_kernel<<<HIST_BLOCKS, 256, 0, stream>>>(node_idx, nbr_idx, ew, cursor, edge_s);
  spmm_kernel<<<N_NODES, 256, 0, stream>>>(row_start, edge_s, M, agg);

  update_kernel<<<MSG_BLOCKS, 256, 0, stream>>>(x, agg, U1f, bu1, U2f, bu2, (float*)d_out);
}